// Round 15
// baseline (802.493 us; speedup 1.0000x reference)
//
#include <hip/hip_runtime.h>
#include <stdint.h>
#include <stddef.h>

#define DEV static __device__ __forceinline__

typedef short short8 __attribute__((ext_vector_type(8)));
typedef short short4v __attribute__((ext_vector_type(4)));
typedef float f32x4 __attribute__((ext_vector_type(4)));
typedef _Float16 half8 __attribute__((ext_vector_type(8)));

// ---------- fp16 helpers ----------
DEV uint16_t f2h(float x){
  union { _Float16 h; uint16_t u; } c; c.h = (_Float16)x; return c.u;
}

DEV f32x4 mfma16h(short8 a, short8 b, f32x4 c){
  union { short8 s; half8 h; } ua, ub; ua.s = a; ub.s = b;
  return __builtin_amdgcn_mfma_f32_16x16x32_f16(ua.h, ub.h, c, 0, 0, 0);
}

// ---------- async global->LDS (16B/lane, wave-uniform LDS base) ----------
typedef const __attribute__((address_space(1))) void* gas1;
typedef __attribute__((address_space(3))) void* las3;
DEV void async16(const void* g, void* l){
  __builtin_amdgcn_global_load_lds((gas1)g, (las3)l, 16, 0, 0);
}

// ---------- swizzled LDS tile access (XOR low-3 oct bits with row&7) ----------
DEV int swzoct(int row, int oct){ return (oct & ~7) | ((oct ^ row) & 7); }
DEV short8 lds_frag(const short* base, int row, int rowOcts, int oct){
  int o = swzoct(row, oct);
  return *(const short8*)(base + row * rowOcts * 8 + o * 8);
}
DEV void lds_store8(short* base, int row, int rowOcts, int oct, short8 v){
  int o = swzoct(row, oct);
  *(short8*)(base + row * rowOcts * 8 + o * 8) = v;
}

// =====================================================================
// Kernel 1: transpose weights to fp16.  WT[n][k]
// =====================================================================
__global__ __launch_bounds__(256) void pa_prep_weights(
    const float* __restrict__ Wk, const float* __restrict__ Wv,
    uint16_t* WkT, uint16_t* WvT){
  int which = blockIdx.y;
  const float* W = which ? Wv : Wk;
  uint16_t* O = which ? WvT : WkT;
  int e0 = (blockIdx.x * 256 + threadIdx.x) * 4;
  #pragma unroll
  for(int c=0;c<4;c++){
    int e = e0 + c; int n = e >> 10, k = e & 1023;
    O[e] = f2h(W[(size_t)k*1024 + n]);
  }
}

// =====================================================================
// Kernel 2 (FUSED): blocks [0,512) = q projection stage 1 (fp64 LDS-tiled);
// blocks [512,4608) = merged fp16 K/V GEMM (round-12 proven structure).
// The two halves touch disjoint data; fusing lets the scheduler overlap
// the fp64 q-projection with the GEMM's idle issue slots.
// =====================================================================
__global__ __launch_bounds__(256) void pa_fused(
    const float* __restrict__ queries, const int* __restrict__ perm,
    const float* __restrict__ Wq, double* __restrict__ qpart,
    const float* __restrict__ keys, const float* __restrict__ values,
    const uint16_t* __restrict__ WkT, const uint16_t* __restrict__ WvT,
    const float* __restrict__ bk, const float* __restrict__ bv,
    uint16_t* __restrict__ k_o, uint16_t* __restrict__ v_t){
  __shared__ alignas(16) char smem[32768];
  int gb = blockIdx.x;
  int t = threadIdx.x;
  if(gb < 512){
    // ---------------- q_stage1 path (identical math/output) -------------
    float* Alds = (float*)smem;             // 96*32 f32 = 12288 B
    float* Blds = (float*)(smem + 12288);   // 32*128 f32 = 16384 B
    int ct = gb & 7, kc = (gb >> 3) & 7, b = gb >> 6;
    int tr = t >> 4, tc = t & 15;
    const float* qb = queries + (size_t)b*4096*1024;
    const float* srcA[3];
    #pragma unroll
    for(int rr=0; rr<3; rr++){
      int chunk = rr*256 + t;
      int row = chunk >> 3, c8 = chunk & 7;
      int rid = (row < 45) ? perm[row] : (row < 90 ? row - 45 : 0);
      srcA[rr] = qb + (size_t)rid*1024 + c8*4;
    }
    const float* srcB[4];
    #pragma unroll
    for(int rr=0; rr<4; rr++){
      int chunk = rr*256 + t;
      int kk = chunk >> 5, c = chunk & 31;
      srcB[rr] = Wq + (size_t)kk*1024 + ct*128 + c*4;
    }
    double acc[6][8];
    #pragma unroll
    for(int i=0;i<6;i++)
      #pragma unroll
      for(int jj=0;jj<8;jj++) acc[i][jj] = 0.0;
    int k0 = kc*128;
    for(int ks=0; ks<4; ks++){
      int kk0 = k0 + ks*32;
      #pragma unroll
      for(int rr=0; rr<3; rr++)
        async16(srcA[rr] + kk0, smem + (rr*256 + t)*16);
      #pragma unroll
      for(int rr=0; rr<4; rr++)
        async16(srcB[rr] + (size_t)kk0*1024, smem + 12288 + (rr*256 + t)*16);
      __syncthreads();
      #pragma unroll
      for(int kk=0; kk<32; kk++){
        double av[6];
        #pragma unroll
        for(int i=0;i<6;i++) av[i] = (double)Alds[(tr*6+i)*32 + kk];
        float4 b0 = *(const float4*)(Blds + kk*128 + tc*8);
        float4 b1 = *(const float4*)(Blds + kk*128 + tc*8 + 4);
        double bv8[8] = {(double)b0.x,(double)b0.y,(double)b0.z,(double)b0.w,
                         (double)b1.x,(double)b1.y,(double)b1.z,(double)b1.w};
        #pragma unroll
        for(int i=0;i<6;i++)
          #pragma unroll
          for(int jj=0;jj<8;jj++)
            acc[i][jj] += av[i]*bv8[jj];
      }
      __syncthreads();
    }
    #pragma unroll
    for(int i=0;i<6;i++){
      int r = tr*6 + i;
      double* dst = qpart + (((size_t)b*96 + r)*8 + kc)*1024 + ct*128 + tc*8;
      #pragma unroll
      for(int jj=0;jj<8;jj++) dst[jj] = acc[i][jj];
    }
    return;
  }
  // ---------------- kv gemm path (identical math/output) ----------------
  short* Ah = (short*)smem;               // 128*64 shorts = 16384 B
  short* Bh = (short*)(smem + 16384);     // 128*64 shorts = 16384 B
  int g = gb - 512;
  const bool TR = (g >= 2048);
  int bid = g & 2047;
  const float* Ag = TR ? values : keys;
  const uint16_t* Bg = TR ? WvT : WkT;
  const float* bias = TR ? bv : bk;
  int wid = t >> 6, lane = t & 63;
  int xcd = bid & 7, slot = bid >> 3;
  int mt = xcd*32 + (slot >> 3), nt = slot & 7;
  int m0 = mt*128, n0 = nt*128;
  int rsub = lane >> 3;
  int soct = (lane & 7) ^ rsub;
  const float*    aF = Ag + (size_t)(m0 + wid*32 + rsub)*1024 + soct*8;
  const uint16_t* b0 = Bg + (size_t)(n0 + wid*32 + rsub)*1024 + soct*8;
  short* lA = Ah + wid*32*64;
  short* lB = Bh + wid*32*64;
  f32x4 acc[4][4];
  #pragma unroll
  for(int i=0;i<4;i++)
    #pragma unroll
    for(int jj=0;jj<4;jj++) acc[i][jj] = (f32x4){0.f,0.f,0.f,0.f};
  int wr = wid >> 1, wc = wid & 1;
  for(int kb=0; kb<16; kb++){
    int ko = kb*64;
    #pragma unroll
    for(int q=0;q<4;q++)
      async16(b0 + ko + q*8*1024, lB + q*512);
    #pragma unroll
    for(int q=0;q<4;q++){
      const float* src = aF + ko + (size_t)q*8*1024;
      float4 u0 = *(const float4*)(src);
      float4 u1 = *(const float4*)(src + 4);
      short8 hv;
      hv[0]=(short)f2h(u0.x); hv[1]=(short)f2h(u0.y);
      hv[2]=(short)f2h(u0.z); hv[3]=(short)f2h(u0.w);
      hv[4]=(short)f2h(u1.x); hv[5]=(short)f2h(u1.y);
      hv[6]=(short)f2h(u1.z); hv[7]=(short)f2h(u1.w);
      *(short8*)(lA + q*512 + lane*8) = hv;
    }
    __syncthreads();
    short8 Af[4][2];
    #pragma unroll
    for(int mf=0;mf<4;mf++)
      #pragma unroll
      for(int k2=0;k2<2;k2++){
        int row = wr*64 + mf*16 + (lane & 15);
        int oct = k2*4 + (lane >> 4);
        Af[mf][k2] = lds_frag(Ah, row, 8, oct);
      }
    #pragma unroll
    for(int nf=0;nf<4;nf++){
      short8 Bf[2];
      #pragma unroll
      for(int k2=0;k2<2;k2++){
        int row = wc*64 + nf*16 + (lane & 15);
        int oct = k2*4 + (lane >> 4);
        Bf[k2] = lds_frag(Bh, row, 8, oct);
      }
      #pragma unroll
      for(int mf=0;mf<4;mf++)
        #pragma unroll
        for(int k2=0;k2<2;k2++)
          acc[mf][nf] = mfma16h(Af[mf][k2], Bf[k2], acc[mf][nf]);
    }
    __syncthreads();
  }
  int b = m0 >> 12, s_base = m0 & 4095;
  #pragma unroll
  for(int mf=0;mf<4;mf++)
    #pragma unroll
    for(int nf=0;nf<4;nf++){
      int srow = s_base + wr*64 + mf*16 + ((lane >> 4) << 2);
      int ncol = n0 + wc*64 + nf*16 + (lane & 15);
      float bia = bias[ncol];
      int h = ncol >> 6, d = ncol & 63;
      if(!TR){
        size_t base = ((((size_t)(b*16 + h))*4096 + srow)*64 + d);
        #pragma unroll
        for(int i=0;i<4;i++)
          k_o[base + (size_t)i*64] = f2h(acc[mf][nf][i] + bia);
      } else {
        short4v pk;
        #pragma unroll
        for(int i=0;i<4;i++) pk[i] = (short)f2h(acc[mf][nf][i] + bia);
        *(short4v*)(v_t + ((((size_t)(b*16 + h))*64 + d)*4096 + srow)) = pk;
      }
    }
}

// =====================================================================
// Kernel 3: q finalize: sum 8 partials + bq -> q_f32 / q_f16
// =====================================================================
__global__ __launch_bounds__(256) void pa_q_finalize(
    const double* __restrict__ qpart, const float* __restrict__ bq,
    float* q_f32, uint16_t* q_f16){
  int slot = blockIdx.x, b = blockIdx.y;
  int j = (slot < 45) ? slot : ((slot >= 48 && slot < 93) ? (45 + slot - 48) : -1);
  #pragma unroll
  for(int c=0;c<4;c++){
    int n = threadIdx.x * 4 + c;
    float v = 0.f;
    if(j >= 0){
      const double* p = qpart + (((size_t)b*96 + j)*8)*1024 + n;
      double s = 0.0;
      #pragma unroll
      for(int kc=0;kc<8;kc++) s += p[(size_t)kc*1024];
      v = (float)(s + (double)bq[n]);
    }
    int h = n >> 6, d = n & 63;
    size_t idx = (((size_t)(b*16 + h))*96 + slot)*64 + d;
    q_f32[idx] = v;
    q_f16[idx] = f2h(v);
  }
}

// =====================================================================
// Kernel 4: P1 — sampled-row stats (top3,sum) + q0-row online (m,Z)
// record per slot: [v1,i1,v2,i2,v3,i3,sum,pad]
// =====================================================================
__global__ __launch_bounds__(256) void pa_p1_stats(
    const uint16_t* __restrict__ q_f16, const uint16_t* __restrict__ khg,
    float* __restrict__ stats){
  __shared__ alignas(16) short qf[96*64], kh[128*64];
  int chunk = blockIdx.x, h = blockIdx.y, b = blockIdx.z;
  int tid = threadIdx.x, wid = tid >> 6, lane = tid & 63;
  const uint16_t* qsf = q_f16 + ((size_t)(b*16 + h))*96*64;
  #pragma unroll
  for(int jj=0;jj<3;jj++){
    int oc = tid*3 + jj;            // 768 octs
    int sl = oc >> 3, o = oc & 7;
    lds_store8(qf, sl, 8, o, *(const short8*)(qsf + sl*64 + o*8));
  }
  float t1v[3][4], t2v[3][4], t3v[3][4], ssum[3][4], mm[3][4], zz[3][4];
  int t1i[3][4], t2i[3][4], t3i[3][4];
  #pragma unroll
  for(int a=0;a<3;a++)
    #pragma unroll
    for(int i=0;i<4;i++){
      t1v[a][i]=-3e38f; t2v[a][i]=-3e38f; t3v[a][i]=-3e38f; ssum[a][i]=0.f;
      mm[a][i]=-3e38f; zz[a][i]=0.f; t1i[a][i]=0; t2i[a][i]=0; t3i[a][i]=0;
    }
  int rsub = lane >> 3, soct = (lane & 7) ^ rsub;
  const uint16_t* khb = khg + (((size_t)(b*16 + h))*4096)*64;
  __syncthreads();
  for(int st=0; st<4; st++){
    int sg0 = chunk*512 + st*128;
    #pragma unroll
    for(int q=0;q<4;q++){
      int row = wid*32 + q*8;
      async16(khb + (size_t)(sg0 + row + rsub)*64 + soct*8, kh + row*64);
    }
    __syncthreads();
    short8 Bf[2][2]; // [nf][k2]
    #pragma unroll
    for(int nf=0;nf<2;nf++)
      #pragma unroll
      for(int k2=0;k2<2;k2++){
        int scol = wid*32 + nf*16 + (lane & 15);
        int oct = k2*4 + (lane >> 4);
        Bf[nf][k2] = lds_frag(kh, scol, 8, oct);
      }
    #pragma unroll
    for(int mf=0;mf<6;mf++){
      short8 af[2];
      #pragma unroll
      for(int k2=0;k2<2;k2++){
        int row = mf*16 + (lane & 15);
        int oct = k2*4 + (lane >> 4);
        af[k2] = lds_frag(qf, row, 8, oct);
      }
      f32x4 a0 = (f32x4){0.f,0.f,0.f,0.f}, a1 = a0;
      #pragma unroll
      for(int k2=0;k2<2;k2++){
        a0 = mfma16h(af[k2], Bf[0][k2], a0);
        a1 = mfma16h(af[k2], Bf[1][k2], a1);
      }
      #pragma unroll
      for(int nf=0;nf<2;nf++){
        int sgl = sg0 + wid*32 + nf*16 + (lane & 15);
        #pragma unroll
        for(int i=0;i<4;i++){
          float v = nf ? a1[i] : a0[i];
          if(mf < 3){
            ssum[mf][i] += v;
            if(v > t1v[mf][i]){
              t3v[mf][i]=t2v[mf][i]; t3i[mf][i]=t2i[mf][i];
              t2v[mf][i]=t1v[mf][i]; t2i[mf][i]=t1i[mf][i];
              t1v[mf][i]=v; t1i[mf][i]=sgl;
            } else if(v > t2v[mf][i]){
              t3v[mf][i]=t2v[mf][i]; t3i[mf][i]=t2i[mf][i];
              t2v[mf][i]=v; t2i[mf][i]=sgl;
            } else if(v > t3v[mf][i]){
              t3v[mf][i]=v; t3i[mf][i]=sgl;
            }
          } else {
            int q = mf - 3;
            float mn = fmaxf(mm[q][i], v);
            zz[q][i] = zz[q][i]*__expf(mm[q][i]-mn) + __expf(v-mn);
            mm[q][i] = mn;
          }
        }
      }
    }
    __syncthreads();
  }
  size_t sbase = (((((size_t)b*16 + h)*8 + chunk)*4 + wid)*96)*8;
  #pragma unroll
  for(int mf=0;mf<3;mf++)
    #pragma unroll
    for(int i=0;i<4;i++){
      float v1=t1v[mf][i], v2=t2v[mf][i], v3=t3v[mf][i], sm=ssum[mf][i];
      int i1=t1i[mf][i], i2=t2i[mf][i], i3=t3i[mf][i];
      #pragma unroll
      for(int msk=1; msk<16; msk<<=1){
        float w1=__shfl_xor(v1,msk,64), w2=__shfl_xor(v2,msk,64), w3=__shfl_xor(v3,msk,64);
        int j1=__shfl_xor(i1,msk,64), j2=__shfl_xor(i2,msk,64), j3=__shfl_xor(i3,msk,64);
        sm += __shfl_xor(sm,msk,64);
        if(w1 > v1){
          float tv; int ti;
          tv=v1; v1=w1; w1=tv; ti=i1; i1=j1; j1=ti;
          tv=v2; v2=w2; w2=tv; ti=i2; i2=j2; j2=ti;
          tv=v3; v3=w3; w3=tv; ti=i3; i3=j3; j3=ti;
        }
        if(w1 > v2){
          v3=v2; i3=i2; v2=w1; i2=j1;
          if(w2 > v3){ v3=w2; i3=j2; }
        } else if(w1 > v3){ v3=w1; i3=j1; }
      }
      if((lane & 15) == 0){
        int sl = mf*16 + ((lane >> 4) << 2) + i;
        float* dst = stats + sbase + (size_t)sl*8;
        dst[0]=v1; dst[1]=__int_as_float(i1); dst[2]=v2; dst[3]=__int_as_float(i2);
        dst[4]=v3; dst[5]=__int_as_float(i3); dst[6]=sm;
      }
    }
  #pragma unroll
  for(int q=0;q<3;q++)
    #pragma unroll
    for(int i=0;i<4;i++){
      float m1=mm[q][i], z1=zz[q][i];
      #pragma unroll
      for(int msk=1; msk<16; msk<<=1){
        float m2=__shfl_xor(m1,msk,64), z2=__shfl_xor(z1,msk,64);
        float mn = fmaxf(m1,m2);
        z1 = z1*__expf(m1-mn) + z2*__expf(m2-mn);
        m1 = mn;
      }
      if((lane & 15) == 0){
        int sl = 48 + q*16 + ((lane >> 4) << 2) + i;
        float* dst = stats + sbase + (size_t)sl*8;
        dst[0]=m1; dst[1]=z1;
      }
    }
}

// =====================================================================
// Kernel 5a: merge partials, wave-parallel rank, mark at-risk rows.
// =====================================================================
__global__ __launch_bounds__(256) void pa_sort_mark(
    const float* __restrict__ stats,
    float* __restrict__ mzfin,
    float* __restrict__ Mv_g, float* __restrict__ Ssum_g,
    int* __restrict__ mlist_g, int* __restrict__ clist_g,
    int* __restrict__ nmark_g){
  int h = blockIdx.x, b = blockIdx.y;
  int bh = b*16 + h;
  __shared__ float Mv[48], Ssum[48];
  __shared__ int I1[48], I2[48], I3[48];
  __shared__ int order[48], mlist[48], flags[48];
  __shared__ int clist[144];
  __shared__ int nmark;
  int t = threadIdx.x;
  const float* sb = stats + (((size_t)bh)*8*4*96)*8;
  if(t < 48) flags[t] = 0;
  if(t < 48){
    float v1=-3e38f, v2=-3e38f, v3=-3e38f, sm=0.f; int i1=0, i2=0, i3=0;
    for(int c=0;c<8;c++)
      for(int w=0;w<4;w++){
        const float* p = sb + (((size_t)c*4 + w)*96 + t)*8;
        float w1=p[0], w2=p[2], w3=p[4];
        int j1=__float_as_int(p[1]), j2=__float_as_int(p[3]), j3=__float_as_int(p[5]);
        sm += p[6];
        if(w1 > v1){
          float tv; int ti;
          tv=v1; v1=w1; w1=tv; ti=i1; i1=j1; j1=ti;
          tv=v2; v2=w2; w2=tv; ti=i2; i2=j2; j2=ti;
          tv=v3; v3=w3; w3=tv; ti=i3; i3=j3; j3=ti;
        }
        if(w1 > v2){
          v3=v2; i3=i2; v2=w1; i2=j1;
          if(w2 > v3){ v3=w2; i3=j2; }
        } else if(w1 > v3){ v3=w1; i3=j1; }
      }
    Mv[t] = v1 - sm*(1.0f/4096.0f);
    I1[t]=i1; I2[t]=i2; I3[t]=i3; Ssum[t]=sm;
  }
  if(t >= 64 && t < 112){
    int i = t - 64;
    float m1=-3e38f, z1=0.f;
    for(int c=0;c<8;c++)
      for(int w=0;w<4;w++){
        const float* p = sb + (((size_t)c*4 + w)*96 + 48 + i)*8;
        float m2=p[0], z2=p[1];
        float mn = fmaxf(m1,m2);
        z1 = z1*__expf(m1-mn) + z2*__expf(m2-mn);
        m1 = mn;
      }
    mzfin[((size_t)bh*48 + i)*2 + 0] = m1;
    mzfin[((size_t)bh*48 + i)*2 + 1] = z1;
  }
  __syncthreads();
  if(t < 64){
    float v = (t < 45) ? Mv[t] : -3e38f;
    int rank = 0;
    #pragma unroll
    for(int j=0;j<45;j++){
      float vj = __shfl(v, j, 64);
      rank += (vj > v) || (vj == v && j < (int)t);
    }
    if(t < 45) order[rank] = t;
  }
  __syncthreads();
  if(t < 44){
    if(Mv[order[t]] - Mv[order[t+1]] < 0.025f){
      flags[order[t]] = 1; flags[order[t+1]] = 1;
    }
  }
  __syncthreads();
  if(t == 0){
    int cnt=0;
    for(int i=0;i<45;i++) if(flags[i]){
      clist[3*cnt]   = I1[i];
      clist[3*cnt+1] = I2[i];
      clist[3*cnt+2] = I3[i];
      mlist[cnt++]=i;
    }
    nmark = cnt;
  }
  __syncthreads();
  int nm = nmark;
  if(t < 48){
    Mv_g[(size_t)bh*48 + t] = Mv[t];
    Ssum_g[(size_t)bh*48 + t] = Ssum[t];
  }
  if(t < nm) mlist_g[(size_t)bh*48 + t] = mlist[t];
  if(t < 3*nm) clist_g[(size_t)bh*144 + t] = clist[t];
  if(t == 0) nmark_g[bh] = nm;
}

// =====================================================================
// Kernel 5b: exact fp64 candidate scores, one block per candidate.
// =====================================================================
__global__ __launch_bounds__(256) void pa_refine(
    const float* __restrict__ keys, const float* __restrict__ Wk,
    const float* __restrict__ q_f32,
    const int* __restrict__ mlist_g, const int* __restrict__ clist_g,
    const int* __restrict__ nmark_g, double* __restrict__ scx_g){
  int cid = blockIdx.x, h = blockIdx.y, b = blockIdx.z;
  int bh = b*16 + h;
  int nc = nmark_g[bh]*3;
  if(cid >= nc) return;
  __shared__ double red[256];
  int t = threadIdx.x;
  int kq = t >> 6, d = t & 63;
  int sidx = clist_g[(size_t)bh*144 + cid];
  int u = mlist_g[(size_t)bh*48 + cid/3];
  const float* krow = keys + ((size_t)b*4096 + sidx)*1024;
  double acc = 0.0;
  int col = h*64 + d;
  #pragma unroll 8
  for(int k=kq*256; k<kq*256+256; k++)
    acc += (double)krow[k] * (double)Wk[(size_t)k*1024 + col];
  red[t] = acc;
  __syncthreads();
  if(t < 64){
    double kd = red[t] + red[64+t] + red[128+t] + red[192+t];
    double sp = kd * (double)q_f32[((size_t)bh*96 + u)*64 + t];
    #pragma unroll
    for(int m=1; m<64; m<<=1) sp += __shfl_xor(sp, m, 64);
    if(t == 0) scx_g[(size_t)bh*144 + cid] = sp;
  }
}

// =====================================================================
// Kernel 5c: apply refined maxima, final wave rank -> invrk
// =====================================================================
__global__ __launch_bounds__(64) void pa_final_rank(
    const float* __restrict__ Mv_g, const float* __restrict__ Ssum_g,
    const int* __restrict__ mlist_g, const int* __restrict__ nmark_g,
    const double* __restrict__ scx_g, int* __restrict__ invrk){
  int h = blockIdx.x, b = blockIdx.y;
  int bh = b*16 + h;
  __shared__ float Mv[48];
  int t = threadIdx.x;
  if(t < 48) Mv[t] = Mv_g[(size_t)bh*48 + t];
  int nm = nmark_g[bh];
  __syncthreads();
  if(t < nm){
    int u = mlist_g[(size_t)bh*48 + t];
    const double* s3 = scx_g + (size_t)bh*144 + 3*t;
    double mx = s3[0];
    if(s3[1] > mx) mx = s3[1];
    if(s3[2] > mx) mx = s3[2];
    Mv[u] = (float)mx - Ssum_g[(size_t)bh*48 + u]*(1.0f/4096.0f);
  }
  __syncthreads();
  float v = (t < 45) ? Mv[t] : -3e38f;
  int rank = 0;
  #pragma unroll
  for(int j=0;j<45;j++){
    float vj = __shfl(v, j, 64);
    rank += (vj > v) || (vj == v && j < (int)t);
  }
  if(t < 45) invrk[(size_t)bh*48 + t] = rank;
}

// =====================================================================
// Kernel 6: P2 — recompute q0 scores, attn = exp(s-m)/Z, PV via MFMA
// =====================================================================
__global__ __launch_bounds__(256) void pa_p2_attn(
    const uint16_t* __restrict__ q_f16, const uint16_t* __restrict__ khg,
    const uint16_t* __restrict__ v_t,
    const float* __restrict__ mzfin, const int* __restrict__ invrk,
    float* __restrict__ attn_out, float* __restrict__ ctx2){
  __shared__ alignas(16) short qf[48*64];
  __shared__ alignas(16) short kh[64*64];
  __shared__ alignas(16) short vT[64*64];
  __shared__ alignas(16) short Pl[48*64];
  int chunk = blockIdx.x, h = blockIdx.y, b = blockIdx.z;
  int tid = threadIdx.x, wid = tid >> 6, lane = tid & 63;
  const uint16_t* qsf = q_f16 + (((size_t)(b*16 + h))*96 + 48)*64;
  for(int oc=tid; oc<384; oc+=256){
    int sl = oc >> 3, o = oc & 7;
    lds_store8(qf, sl, 8, o, *(const short8*)(qsf + sl*64 + o*8));
  }
  float mreg[3][4], invz[3][4];
  int rrk[3][4];
  #pragma unroll
  for(int mf=0;mf<3;mf++)
    #pragma unroll
    for(int i=0;i<4;i++){
      int u = mf*16 + ((lane >> 4) << 2) + i;
      mreg[mf][i] = mzfin[(((size_t)(b*16 + h))*48 + u)*2 + 0];
      invz[mf][i] = 1.f / mzfin[(((size_t)(b*16 + h))*48 + u)*2 + 1];
      rrk[mf][i] = invrk[((size_t)(b*16 + h))*48 + u];
    }
  f32x4 ctx[3];
  #pragma unroll
  for(int mf=0;mf<3;mf++) ctx[mf] = (f32x4){0.f,0.f,0.f,0.f};
  int rsub = lane >> 3, soct = (lane & 7) ^ rsub;
  const uint16_t* khb = khg + (((size_t)(b*16 + h))*4096)*64;
  const uint16_t* vtb = v_t + (((size_t)(b*16 + h))*64)*4096;
  __syncthreads();
  for(int st=0; st<8; st++){
    int sg0 = chunk*512 + st*64;
    #pragma unroll
    for(int q=0;q<2;q++){
      int row = wid*16 + q*8;
      async16(khb + (size_t)(sg0 + row + rsub)*64 + soct*8, kh + row*64);
      async16(vtb + (size_t)(row + rsub)*4096 + sg0 + soct*8, vT + row*64);
    }
    __syncthreads();
    short8 Bf[2];
    #pragma unroll
    for(int k2=0;k2<2;k2++){
      int scol = wid*16 + (lane & 15);
      int oct = k2*4 + (lane >> 4);
      Bf[k2] = lds_frag(kh, scol, 8, oct);
    }
    #pragma unroll
    for(int mf=0;mf<3;mf++){
      short8 af[2];
      #pragma unroll
      for(int k2=0;k2<2;k2++){
        int row = mf*16 + (lane & 15);
        int oct = k2*4 + (lane >> 4);
        af[k2] = lds_frag(qf, row, 8, oct);
      }
      f32x4 a0 = (f32x4){0.f,0.f,0.f,0.f};
      #pragma unroll
      for(int k2=0;k2<2;k2++)
        a0 = mfma16h(af[k2], Bf[k2], a0);
      int scl = wid*16 + (lane & 15);
      #pragma unroll
      for(int i=0;i<4;i++){
        int u = mf*16 + ((lane >> 4) << 2) + i;
        float p = __expf(a0[i] - mreg[mf][i]) * invz[mf][i];
        if(u < 45){
          attn_out[(((size_t)(b*16 + h))*45 + rrk[mf][i])*4096 + sg0 + scl] = p;
        }
        int oct = scl >> 3;
        int o = (oct ^ (u & 7)) & 7;
        Pl[u*64 + o*8 + (scl & 7)] = (short)f2h(p);
      }
    }
    __syncthreads();
    #pragma unroll
    for(int k2=0;k2<2;k2++){
      int oct = k2*4 + (lane >> 4);
      int drow = wid*16 + (lane & 15);
      short8 bv = lds_frag(vT, drow, 8, oct);
      #pragma unroll
      for(int mf=0;mf<3;mf++){
        int row = mf*16 + (lane & 15);
        short8 ap = lds_frag(Pl, row, 8, oct);
        ctx[mf] = mfma16h(ap, bv, ctx[mf]);
      }
    }
    __syncthreads();
  }
  #pragma unroll
  for(int mf=0;mf<3;mf++)
    #pragma unroll
    for(int i=0;i<4;i++){
      int u = mf*16 + ((lane >> 4) << 2) + i;
      if(u < 45){
        int d = wid*16 + (lane & 15);
        ctx2[(((size_t)chunk*8 + b)*45 + rrk[mf][i])*1024 + h*64 + d] = ctx[mf][i];
      }
    }
}

// =====================================================================
// Kernel 7a: output partials — split-K by 4 for occupancy.
// =====================================================================
__global__ __launch_bounds__(256) void pa_out_part(
    const float* __restrict__ ctx2, const float* __restrict__ Wo,
    float* __restrict__ opart){
  __shared__ float cl[8][256];
  int bx = blockIdx.x, by = blockIdx.y, kc = blockIdx.z;
  int t = threadIdx.x;
  for(int e=t; e<8*256; e+=256){
    int rr = e >> 8, kk = e & 255;
    size_t grow = (size_t)by*8 + rr;
    float s = 0.f;
    #pragma unroll
    for(int c=0;c<8;c++) s += ctx2[((size_t)c*360 + grow)*1024 + kc*256 + kk];
    cl[rr][kk] = s;
  }
  __syncthreads();
  int quad = t & 63, rg = t >> 6;
  int n = bx*256 + quad*4;
  float acc[2][4];
  #pragma unroll
  for(int rr=0;rr<2;rr++)
    #pragma unroll
    for(int c=0;c<4;c++) acc[rr][c]=0.f;
  for(int k=0;k<256;k++){
    float4 w = *(const float4*)(Wo + (size_t)(kc*256 + k)*1024 + n);
    float c0 = cl[rg*2][k], c1 = cl[rg*2+1][k];
    acc[0][0] += c0*w.x; acc[0][1] += c0*w.y; acc[0][2] += c0*w.z; acc[0][3] += c0*w.w;
    acc[1][0] += c1*w.x; acc[1][1] += c1*w.y; acc[1][2] += c1*w.z; acc[1][3] += c1*w.w;
  }
  #pragma unroll
  for(int rr=0;rr<2;rr++){
    size_t grow = (size_t)by*8 + rg*2 + rr;
    #pragma unroll
    for(int c=0;c<4;c++)
      opart[((size_t)kc*360 + grow)*1024 + n + c] = acc[rr][c];
  }
}

// =====================================================================
// Kernel 7b: out = sum of 4 k-partials + bias (deterministic order)
// =====================================================================
__global__ __launch_bounds__(256) void pa_out_reduce(
    const float* __restrict__ opart, const float* __restrict__ bo,
    float* __restrict__ out){
  size_t e = (size_t)blockIdx.x*256 + threadIdx.x;
  const size_t N = (size_t)360*1024;
  if(e >= N) return;
  float s = ((opart[e] + opart[e + N]) + opart[e + 2*N]) + opart[e + 3*N];
  out[e] = s + bo[e & 1023];
}

// =====================================================================
extern "C" void kernel_launch(void* const* d_in, const int* in_sizes, int n_in,
                              void* d_out, int out_size, void* d_ws, size_t ws_size,
                              hipStream_t stream){
  const float* queries = (const float*)d_in[0];
  const float* keys    = (const float*)d_in[1];
  const float* values  = (const float*)d_in[2];
  const int*   perm    = (const int*)d_in[3];
  const float* Wq = (const float*)d_in[4]; const float* bq = (const float*)d_in[5];
  const float* Wk = (const float*)d_in[6]; const float* bk = (const float*)d_in[7];
  const float* Wv = (const float*)d_in[8]; const float* bv = (const float*)d_in[9];
  const float* Wo = (const float*)d_in[10]; const float* bo = (const float*)d_in[11];

  char* ws = (char*)d_ws;
  const size_t SZ = (size_t)33554432;          // 32M elements
  uint16_t* k_o   = (uint16_t*)(ws + SZ*4);                 // 67.1 MB
  uint16_t* v_t   = (uint16_t*)(ws + SZ*6);                 // 67.1 MB
  uint16_t* WkT   = (uint16_t*)(ws + SZ*8);                 // 2 MB
  uint16_t* WvT   = (uint16_t*)(ws + SZ*8 + 2097152);       // 2 MB
  float*    q_f32 = (float*)   (ws + SZ*8 + 4194304);       // 3.1 MB
  uint16_t* q_f16 = (uint16_t*)(ws + SZ*8 + 7340032);       // 1.6 MB

  // time-exclusive aliases (qpart dies before p1_stats writes stats;
  // opart written only after p2_attn):
  char* rg = ws + SZ*2;
  double* qpart   = (double*)rg;                      // 50,331,648 B
  float*  stats   = (float*)rg;                       // 12,582,912 B
  float*  mzfin   = (float*)(rg + 12582912);          //     49,152
  int*    invrk   = (int*)  (rg + 12632064);          //     24,576
  float*  ctx2    = (float*)(rg + 12656640);          // 11,796,480
  float*  Mv_g    = (float*)(rg + 24453120);          //     24,576
  float*  Ssum_g  = (float*)(rg + 24477696);          //     24,576
  int*    mlist_g = (int*)  (rg + 24502272);          //     24,576
  int*    clist_g = (int*)  (rg + 24526848);          //     73,728
  int*    nmark_g = (int*)  (rg + 24600576);          //        512
  double* scx_g   = (double*)(rg + 24601088);         //    147,456
  float*  opart   = (float*)(rg + 24748544);          //  5,898,240

  float* out  = (float*)d_out;
  float* attn = out + (size_t)360*1024;

  pa_prep_weights<<<dim3(1024,2), 256, 0, stream>>>(Wk, Wv, WkT, WvT);
  pa_fused<<<4608, 256, 0, stream>>>(queries, perm, Wq, qpart,
                                     keys, values, WkT, WvT, bk, bv, k_o, v_t);
  pa_q_finalize<<<dim3(96,8), 256, 0, stream>>>(qpart, bq, q_f32, q_f16);
  pa_p1_stats<<<dim3(8,16,8), 256, 0, stream>>>(q_f16, k_o, stats);
  pa_sort_mark<<<dim3(16,8), 256, 0, stream>>>(stats, mzfin, Mv_g, Ssum_g, mlist_g, clist_g, nmark_g);
  pa_refine<<<dim3(135,16,8), 256, 0, stream>>>(keys, Wk, q_f32, mlist_g, clist_g, nmark_g, scx_g);
  pa_final_rank<<<dim3(16,8), 64, 0, stream>>>(Mv_g, Ssum_g, mlist_g, nmark_g, scx_g, invrk);
  pa_p2_attn<<<dim3(8,16,8), 256, 0, stream>>>(q_f16, k_o, v_t, mzfin, invrk, attn, ctx2);
  pa_out_part<<<dim3(4,45,4), 256, 0, stream>>>(ctx2, Wo, opart);
  pa_out_reduce<<<1440, 256, 0, stream>>>(opart, bo, out);
}

// Round 16
// 562.935 us; speedup vs baseline: 1.4256x; 1.4256x over previous
//
#include <hip/hip_runtime.h>
#include <stdint.h>
#include <stddef.h>

#define DEV static __device__ __forceinline__

typedef short short8 __attribute__((ext_vector_type(8)));
typedef short short4v __attribute__((ext_vector_type(4)));
typedef float f32x4 __attribute__((ext_vector_type(4)));
typedef _Float16 half8 __attribute__((ext_vector_type(8)));

// ---------- fp16 helpers ----------
DEV uint16_t f2h(float x){
  union { _Float16 h; uint16_t u; } c; c.h = (_Float16)x; return c.u;
}

DEV f32x4 mfma16h(short8 a, short8 b, f32x4 c){
  union { short8 s; half8 h; } ua, ub; ua.s = a; ub.s = b;
  return __builtin_amdgcn_mfma_f32_16x16x32_f16(ua.h, ub.h, c, 0, 0, 0);
}

// ---------- async global->LDS (16B/lane, wave-uniform LDS base) ----------
typedef const __attribute__((address_space(1))) void* gas1;
typedef __attribute__((address_space(3))) void* las3;
DEV void async16(const void* g, void* l){
  __builtin_amdgcn_global_load_lds((gas1)g, (las3)l, 16, 0, 0);
}

// ---------- swizzled LDS tile access (XOR low-3 oct bits with row&7) ----------
DEV int swzoct(int row, int oct){ return (oct & ~7) | ((oct ^ row) & 7); }
DEV short8 lds_frag(const short* base, int row, int rowOcts, int oct){
  int o = swzoct(row, oct);
  return *(const short8*)(base + row * rowOcts * 8 + o * 8);
}
DEV void lds_store8(short* base, int row, int rowOcts, int oct, short8 v){
  int o = swzoct(row, oct);
  *(short8*)(base + row * rowOcts * 8 + o * 8) = v;
}

// =====================================================================
// Kernel 1: transpose weights to fp16.  WT[n][k]
// =====================================================================
__global__ __launch_bounds__(256) void pa_prep_weights(
    const float* __restrict__ Wk, const float* __restrict__ Wv,
    uint16_t* WkT, uint16_t* WvT){
  int which = blockIdx.y;
  const float* W = which ? Wv : Wk;
  uint16_t* O = which ? WvT : WkT;
  int e0 = (blockIdx.x * 256 + threadIdx.x) * 4;
  #pragma unroll
  for(int c=0;c<4;c++){
    int e = e0 + c; int n = e >> 10, k = e & 1023;
    O[e] = f2h(W[(size_t)k*1024 + n]);
  }
}

// =====================================================================
// Kernel 2: q projection stage 1 — LDS-tiled fp64-accumulate GEMM.
// =====================================================================
__global__ __launch_bounds__(256) void pa_q_stage1(
    const float* __restrict__ queries, const int* __restrict__ perm,
    const float* __restrict__ Wq, double* __restrict__ qpart){
  __shared__ alignas(16) float Alds[96*32];   // [row][kk]
  __shared__ alignas(16) float Blds[32*128];  // [kk][col]
  int ct = blockIdx.x, kc = blockIdx.y, b = blockIdx.z;
  int t = threadIdx.x;
  int tr = t >> 4, tc = t & 15;
  const float* qb = queries + (size_t)b*4096*1024;
  const float* srcA[3];
  #pragma unroll
  for(int rr=0; rr<3; rr++){
    int chunk = rr*256 + t;
    int row = chunk >> 3, c8 = chunk & 7;
    int rid = (row < 45) ? perm[row] : (row < 90 ? row - 45 : 0);
    srcA[rr] = qb + (size_t)rid*1024 + c8*4;
  }
  const float* srcB[4];
  #pragma unroll
  for(int rr=0; rr<4; rr++){
    int chunk = rr*256 + t;
    int kk = chunk >> 5, c = chunk & 31;
    srcB[rr] = Wq + (size_t)kk*1024 + ct*128 + c*4;
  }
  double acc[6][8];
  #pragma unroll
  for(int i=0;i<6;i++)
    #pragma unroll
    for(int jj=0;jj<8;jj++) acc[i][jj] = 0.0;
  int k0 = kc*128;
  for(int ks=0; ks<4; ks++){
    int kk0 = k0 + ks*32;
    #pragma unroll
    for(int rr=0; rr<3; rr++)
      async16(srcA[rr] + kk0, (char*)Alds + (rr*256 + t)*16);
    #pragma unroll
    for(int rr=0; rr<4; rr++)
      async16(srcB[rr] + (size_t)kk0*1024, (char*)Blds + (rr*256 + t)*16);
    __syncthreads();
    #pragma unroll
    for(int kk=0; kk<32; kk++){
      double av[6];
      #pragma unroll
      for(int i=0;i<6;i++) av[i] = (double)Alds[(tr*6+i)*32 + kk];
      float4 b0 = *(const float4*)(Blds + kk*128 + tc*8);
      float4 b1 = *(const float4*)(Blds + kk*128 + tc*8 + 4);
      double bv[8] = {(double)b0.x,(double)b0.y,(double)b0.z,(double)b0.w,
                      (double)b1.x,(double)b1.y,(double)b1.z,(double)b1.w};
      #pragma unroll
      for(int i=0;i<6;i++)
        #pragma unroll
        for(int jj=0;jj<8;jj++)
          acc[i][jj] += av[i]*bv[jj];
    }
    __syncthreads();
  }
  #pragma unroll
  for(int i=0;i<6;i++){
    int r = tr*6 + i;
    double* dst = qpart + (((size_t)b*96 + r)*8 + kc)*1024 + ct*128 + tc*8;
    #pragma unroll
    for(int jj=0;jj<8;jj++) dst[jj] = acc[i][jj];
  }
}

// =====================================================================
// Kernel 3: q finalize: sum 8 partials + bq -> q_f32 / q_f16
// =====================================================================
__global__ __launch_bounds__(256) void pa_q_finalize(
    const double* __restrict__ qpart, const float* __restrict__ bq,
    float* q_f32, uint16_t* q_f16){
  int slot = blockIdx.x, b = blockIdx.y;
  int j = (slot < 45) ? slot : ((slot >= 48 && slot < 93) ? (45 + slot - 48) : -1);
  #pragma unroll
  for(int c=0;c<4;c++){
    int n = threadIdx.x * 4 + c;
    float v = 0.f;
    if(j >= 0){
      const double* p = qpart + (((size_t)b*96 + j)*8)*1024 + n;
      double s = 0.0;
      #pragma unroll
      for(int kc=0;kc<8;kc++) s += p[(size_t)kc*1024];
      v = (float)(s + (double)bq[n]);
    }
    int h = n >> 6, d = n & 63;
    size_t idx = (((size_t)(b*16 + h))*96 + slot)*64 + d;
    q_f32[idx] = v;
    q_f16[idx] = f2h(v);
  }
}

// =====================================================================
// Kernel 4: merged fp16 GEMM (round-12 proven serial fused version):
// 128x128/BK=64, A fused fp32->fp16 (same pre-swizzled segment ->
// identical LDS image), B via global_load_lds.
// y==0: k = keys@Wk -> k_o fp16 [b][h][s][64]
// y==1: v = values@Wv -> v_t fp16 [b][h][d][s]
// =====================================================================
__global__ __launch_bounds__(256) void pa_kv_gemm(
    const float* __restrict__ keys, const float* __restrict__ values,
    const uint16_t* __restrict__ WkT, const uint16_t* __restrict__ WvT,
    const float* __restrict__ bk, const float* __restrict__ bv,
    uint16_t* __restrict__ k_o, uint16_t* __restrict__ v_t){
  __shared__ alignas(16) short Ah[128*64], Bh[128*64];
  const bool TR = (blockIdx.y == 1);
  const float* Ag = TR ? values : keys;
  const uint16_t* Bg = TR ? WvT : WkT;
  const float* bias = TR ? bv : bk;
  int tid = threadIdx.x, wid = tid >> 6, lane = tid & 63;
  int bid = blockIdx.x;
  int xcd = bid & 7, slot = bid >> 3;
  int mt = xcd*32 + (slot >> 3), nt = slot & 7;
  int m0 = mt*128, n0 = nt*128;
  int rsub = lane >> 3;
  int soct = (lane & 7) ^ rsub;
  const float*    aF = Ag + (size_t)(m0 + wid*32 + rsub)*1024 + soct*8;
  const uint16_t* b0 = Bg + (size_t)(n0 + wid*32 + rsub)*1024 + soct*8;
  short* lA = Ah + wid*32*64;
  short* lB = Bh + wid*32*64;
  f32x4 acc[4][4];
  #pragma unroll
  for(int i=0;i<4;i++)
    #pragma unroll
    for(int jj=0;jj<4;jj++) acc[i][jj] = (f32x4){0.f,0.f,0.f,0.f};
  int wr = wid >> 1, wc = wid & 1;
  for(int kb=0; kb<16; kb++){
    int ko = kb*64;
    // B: async global->LDS (issued first, stays in flight during A cvt)
    #pragma unroll
    for(int q=0;q<4;q++)
      async16(b0 + ko + q*8*1024, lB + q*512);
    // A: reg-staged fp32 load + cvt + ds_write to the identical slot
    #pragma unroll
    for(int q=0;q<4;q++){
      const float* src = aF + ko + (size_t)q*8*1024;
      float4 u0 = *(const float4*)(src);
      float4 u1 = *(const float4*)(src + 4);
      short8 hv;
      hv[0]=(short)f2h(u0.x); hv[1]=(short)f2h(u0.y);
      hv[2]=(short)f2h(u0.z); hv[3]=(short)f2h(u0.w);
      hv[4]=(short)f2h(u1.x); hv[5]=(short)f2h(u1.y);
      hv[6]=(short)f2h(u1.z); hv[7]=(short)f2h(u1.w);
      *(short8*)(lA + q*512 + lane*8) = hv;
    }
    __syncthreads();
    short8 Af[4][2];
    #pragma unroll
    for(int mf=0;mf<4;mf++)
      #pragma unroll
      for(int k2=0;k2<2;k2++){
        int row = wr*64 + mf*16 + (lane & 15);
        int oct = k2*4 + (lane >> 4);
        Af[mf][k2] = lds_frag(Ah, row, 8, oct);
      }
    #pragma unroll
    for(int nf=0;nf<4;nf++){
      short8 Bf[2];
      #pragma unroll
      for(int k2=0;k2<2;k2++){
        int row = wc*64 + nf*16 + (lane & 15);
        int oct = k2*4 + (lane >> 4);
        Bf[k2] = lds_frag(Bh, row, 8, oct);
      }
      #pragma unroll
      for(int mf=0;mf<4;mf++)
        #pragma unroll
        for(int k2=0;k2<2;k2++)
          acc[mf][nf] = mfma16h(Af[mf][k2], Bf[k2], acc[mf][nf]);
    }
    __syncthreads();
  }
  int b = m0 >> 12, s_base = m0 & 4095;
  #pragma unroll
  for(int mf=0;mf<4;mf++)
    #pragma unroll
    for(int nf=0;nf<4;nf++){
      int srow = s_base + wr*64 + mf*16 + ((lane >> 4) << 2);
      int ncol = n0 + wc*64 + nf*16 + (lane & 15);
      float bia = bias[ncol];
      int h = ncol >> 6, d = ncol & 63;
      if(!TR){
        size_t base = ((((size_t)(b*16 + h))*4096 + srow)*64 + d);
        #pragma unroll
        for(int i=0;i<4;i++)
          k_o[base + (size_t)i*64] = f2h(acc[mf][nf][i] + bia);
      } else {
        short4v pk;
        #pragma unroll
        for(int i=0;i<4;i++) pk[i] = (short)f2h(acc[mf][nf][i] + bia);
        *(short4v*)(v_t + ((((size_t)(b*16 + h))*64 + d)*4096 + srow)) = pk;
      }
    }
}

// =====================================================================
// Kernel 5: P1 — sampled-row stats (top3,sum) + q0-row online (m,Z)
// record per slot: [v1,i1,v2,i2,v3,i3,sum,pad]
// =====================================================================
__global__ __launch_bounds__(256) void pa_p1_stats(
    const uint16_t* __restrict__ q_f16, const uint16_t* __restrict__ khg,
    float* __restrict__ stats){
  __shared__ alignas(16) short qf[96*64], kh[128*64];
  int chunk = blockIdx.x, h = blockIdx.y, b = blockIdx.z;
  int tid = threadIdx.x, wid = tid >> 6, lane = tid & 63;
  const uint16_t* qsf = q_f16 + ((size_t)(b*16 + h))*96*64;
  #pragma unroll
  for(int jj=0;jj<3;jj++){
    int oc = tid*3 + jj;            // 768 octs
    int sl = oc >> 3, o = oc & 7;
    lds_store8(qf, sl, 8, o, *(const short8*)(qsf + sl*64 + o*8));
  }
  float t1v[3][4], t2v[3][4], t3v[3][4], ssum[3][4], mm[3][4], zz[3][4];
  int t1i[3][4], t2i[3][4], t3i[3][4];
  #pragma unroll
  for(int a=0;a<3;a++)
    #pragma unroll
    for(int i=0;i<4;i++){
      t1v[a][i]=-3e38f; t2v[a][i]=-3e38f; t3v[a][i]=-3e38f; ssum[a][i]=0.f;
      mm[a][i]=-3e38f; zz[a][i]=0.f; t1i[a][i]=0; t2i[a][i]=0; t3i[a][i]=0;
    }
  int rsub = lane >> 3, soct = (lane & 7) ^ rsub;
  const uint16_t* khb = khg + (((size_t)(b*16 + h))*4096)*64;
  __syncthreads();
  for(int st=0; st<4; st++){
    int sg0 = chunk*512 + st*128;
    #pragma unroll
    for(int q=0;q<4;q++){
      int row = wid*32 + q*8;
      async16(khb + (size_t)(sg0 + row + rsub)*64 + soct*8, kh + row*64);
    }
    __syncthreads();
    short8 Bf[2][2]; // [nf][k2]
    #pragma unroll
    for(int nf=0;nf<2;nf++)
      #pragma unroll
      for(int k2=0;k2<2;k2++){
        int scol = wid*32 + nf*16 + (lane & 15);
        int oct = k2*4 + (lane >> 4);
        Bf[nf][k2] = lds_frag(kh, scol, 8, oct);
      }
    #pragma unroll
    for(int mf=0;mf<6;mf++){
      short8 af[2];
      #pragma unroll
      for(int k2=0;k2<2;k2++){
        int row = mf*16 + (lane & 15);
        int oct = k2*4 + (lane >> 4);
        af[k2] = lds_frag(qf, row, 8, oct);
      }
      f32x4 a0 = (f32x4){0.f,0.f,0.f,0.f}, a1 = a0;
      #pragma unroll
      for(int k2=0;k2<2;k2++){
        a0 = mfma16h(af[k2], Bf[0][k2], a0);
        a1 = mfma16h(af[k2], Bf[1][k2], a1);
      }
      #pragma unroll
      for(int nf=0;nf<2;nf++){
        int sgl = sg0 + wid*32 + nf*16 + (lane & 15);
        #pragma unroll
        for(int i=0;i<4;i++){
          float v = nf ? a1[i] : a0[i];
          if(mf < 3){
            ssum[mf][i] += v;
            if(v > t1v[mf][i]){
              t3v[mf][i]=t2v[mf][i]; t3i[mf][i]=t2i[mf][i];
              t2v[mf][i]=t1v[mf][i]; t2i[mf][i]=t1i[mf][i];
              t1v[mf][i]=v; t1i[mf][i]=sgl;
            } else if(v > t2v[mf][i]){
              t3v[mf][i]=t2v[mf][i]; t3i[mf][i]=t2i[mf][i];
              t2v[mf][i]=v; t2i[mf][i]=sgl;
            } else if(v > t3v[mf][i]){
              t3v[mf][i]=v; t3i[mf][i]=sgl;
            }
          } else {
            int q = mf - 3;
            float mn = fmaxf(mm[q][i], v);
            zz[q][i] = zz[q][i]*__expf(mm[q][i]-mn) + __expf(v-mn);
            mm[q][i] = mn;
          }
        }
      }
    }
    __syncthreads();
  }
  size_t sbase = (((((size_t)b*16 + h)*8 + chunk)*4 + wid)*96)*8;
  #pragma unroll
  for(int mf=0;mf<3;mf++)
    #pragma unroll
    for(int i=0;i<4;i++){
      float v1=t1v[mf][i], v2=t2v[mf][i], v3=t3v[mf][i], sm=ssum[mf][i];
      int i1=t1i[mf][i], i2=t2i[mf][i], i3=t3i[mf][i];
      #pragma unroll
      for(int msk=1; msk<16; msk<<=1){
        float w1=__shfl_xor(v1,msk,64), w2=__shfl_xor(v2,msk,64), w3=__shfl_xor(v3,msk,64);
        int j1=__shfl_xor(i1,msk,64), j2=__shfl_xor(i2,msk,64), j3=__shfl_xor(i3,msk,64);
        sm += __shfl_xor(sm,msk,64);
        if(w1 > v1){
          float tv; int ti;
          tv=v1; v1=w1; w1=tv; ti=i1; i1=j1; j1=ti;
          tv=v2; v2=w2; w2=tv; ti=i2; i2=j2; j2=ti;
          tv=v3; v3=w3; w3=tv; ti=i3; i3=j3; j3=ti;
        }
        if(w1 > v2){
          v3=v2; i3=i2; v2=w1; i2=j1;
          if(w2 > v3){ v3=w2; i3=j2; }
        } else if(w1 > v3){ v3=w1; i3=j1; }
      }
      if((lane & 15) == 0){
        int sl = mf*16 + ((lane >> 4) << 2) + i;
        float* dst = stats + sbase + (size_t)sl*8;
        dst[0]=v1; dst[1]=__int_as_float(i1); dst[2]=v2; dst[3]=__int_as_float(i2);
        dst[4]=v3; dst[5]=__int_as_float(i3); dst[6]=sm;
      }
    }
  #pragma unroll
  for(int q=0;q<3;q++)
    #pragma unroll
    for(int i=0;i<4;i++){
      float m1=mm[q][i], z1=zz[q][i];
      #pragma unroll
      for(int msk=1; msk<16; msk<<=1){
        float m2=__shfl_xor(m1,msk,64), z2=__shfl_xor(z1,msk,64);
        float mn = fmaxf(m1,m2);
        z1 = z1*__expf(m1-mn) + z2*__expf(m2-mn);
        m1 = mn;
      }
      if((lane & 15) == 0){
        int sl = 48 + q*16 + ((lane >> 4) << 2) + i;
        float* dst = stats + sbase + (size_t)sl*8;
        dst[0]=m1; dst[1]=z1;
      }
    }
}

// =====================================================================
// Kernel 6a: merge partials, wave-parallel rank, mark at-risk rows.
// =====================================================================
__global__ __launch_bounds__(256) void pa_sort_mark(
    const float* __restrict__ stats,
    float* __restrict__ mzfin,
    float* __restrict__ Mv_g, float* __restrict__ Ssum_g,
    int* __restrict__ mlist_g, int* __restrict__ clist_g,
    int* __restrict__ nmark_g){
  int h = blockIdx.x, b = blockIdx.y;
  int bh = b*16 + h;
  __shared__ float Mv[48], Ssum[48];
  __shared__ int I1[48], I2[48], I3[48];
  __shared__ int order[48], mlist[48], flags[48];
  __shared__ int clist[144];
  __shared__ int nmark;
  int t = threadIdx.x;
  const float* sb = stats + (((size_t)bh)*8*4*96)*8;
  if(t < 48) flags[t] = 0;
  if(t < 48){
    float v1=-3e38f, v2=-3e38f, v3=-3e38f, sm=0.f; int i1=0, i2=0, i3=0;
    for(int c=0;c<8;c++)
      for(int w=0;w<4;w++){
        const float* p = sb + (((size_t)c*4 + w)*96 + t)*8;
        float w1=p[0], w2=p[2], w3=p[4];
        int j1=__float_as_int(p[1]), j2=__float_as_int(p[3]), j3=__float_as_int(p[5]);
        sm += p[6];
        if(w1 > v1){
          float tv; int ti;
          tv=v1; v1=w1; w1=tv; ti=i1; i1=j1; j1=ti;
          tv=v2; v2=w2; w2=tv; ti=i2; i2=j2; j2=ti;
          tv=v3; v3=w3; w3=tv; ti=i3; i3=j3; j3=ti;
        }
        if(w1 > v2){
          v3=v2; i3=i2; v2=w1; i2=j1;
          if(w2 > v3){ v3=w2; i3=j2; }
        } else if(w1 > v3){ v3=w1; i3=j1; }
      }
    Mv[t] = v1 - sm*(1.0f/4096.0f);
    I1[t]=i1; I2[t]=i2; I3[t]=i3; Ssum[t]=sm;
  }
  if(t >= 64 && t < 112){
    int i = t - 64;
    float m1=-3e38f, z1=0.f;
    for(int c=0;c<8;c++)
      for(int w=0;w<4;w++){
        const float* p = sb + (((size_t)c*4 + w)*96 + 48 + i)*8;
        float m2=p[0], z2=p[1];
        float mn = fmaxf(m1,m2);
        z1 = z1*__expf(m1-mn) + z2*__expf(m2-mn);
        m1 = mn;
      }
    mzfin[((size_t)bh*48 + i)*2 + 0] = m1;
    mzfin[((size_t)bh*48 + i)*2 + 1] = z1;
  }
  __syncthreads();
  if(t < 64){
    float v = (t < 45) ? Mv[t] : -3e38f;
    int rank = 0;
    #pragma unroll
    for(int j=0;j<45;j++){
      float vj = __shfl(v, j, 64);
      rank += (vj > v) || (vj == v && j < (int)t);
    }
    if(t < 45) order[rank] = t;
  }
  __syncthreads();
  if(t < 44){
    if(Mv[order[t]] - Mv[order[t+1]] < 0.025f){
      flags[order[t]] = 1; flags[order[t+1]] = 1;
    }
  }
  __syncthreads();
  if(t == 0){
    int cnt=0;
    for(int i=0;i<45;i++) if(flags[i]){
      clist[3*cnt]   = I1[i];
      clist[3*cnt+1] = I2[i];
      clist[3*cnt+2] = I3[i];
      mlist[cnt++]=i;
    }
    nmark = cnt;
  }
  __syncthreads();
  int nm = nmark;
  if(t < 48){
    Mv_g[(size_t)bh*48 + t] = Mv[t];
    Ssum_g[(size_t)bh*48 + t] = Ssum[t];
  }
  if(t < nm) mlist_g[(size_t)bh*48 + t] = mlist[t];
  if(t < 3*nm) clist_g[(size_t)bh*144 + t] = clist[t];
  if(t == 0) nmark_g[bh] = nm;
}

// =====================================================================
// Kernel 6b: exact fp64 candidate scores, one block per candidate.
// =====================================================================
__global__ __launch_bounds__(256) void pa_refine(
    const float* __restrict__ keys, const float* __restrict__ Wk,
    const float* __restrict__ q_f32,
    const int* __restrict__ mlist_g, const int* __restrict__ clist_g,
    const int* __restrict__ nmark_g, double* __restrict__ scx_g){
  int cid = blockIdx.x, h = blockIdx.y, b = blockIdx.z;
  int bh = b*16 + h;
  int nc = nmark_g[bh]*3;
  if(cid >= nc) return;
  __shared__ double red[256];
  int t = threadIdx.x;
  int kq = t >> 6, d = t & 63;
  int sidx = clist_g[(size_t)bh*144 + cid];
  int u = mlist_g[(size_t)bh*48 + cid/3];
  const float* krow = keys + ((size_t)b*4096 + sidx)*1024;
  double acc = 0.0;
  int col = h*64 + d;
  #pragma unroll 8
  for(int k=kq*256; k<kq*256+256; k++)
    acc += (double)krow[k] * (double)Wk[(size_t)k*1024 + col];
  red[t] = acc;
  __syncthreads();
  if(t < 64){
    double kd = red[t] + red[64+t] + red[128+t] + red[192+t];
    double sp = kd * (double)q_f32[((size_t)bh*96 + u)*64 + t];
    #pragma unroll
    for(int m=1; m<64; m<<=1) sp += __shfl_xor(sp, m, 64);
    if(t == 0) scx_g[(size_t)bh*144 + cid] = sp;
  }
}

// =====================================================================
// Kernel 6c: apply refined maxima, final wave rank -> invrk
// =====================================================================
__global__ __launch_bounds__(64) void pa_final_rank(
    const float* __restrict__ Mv_g, const float* __restrict__ Ssum_g,
    const int* __restrict__ mlist_g, const int* __restrict__ nmark_g,
    const double* __restrict__ scx_g, int* __restrict__ invrk){
  int h = blockIdx.x, b = blockIdx.y;
  int bh = b*16 + h;
  __shared__ float Mv[48];
  int t = threadIdx.x;
  if(t < 48) Mv[t] = Mv_g[(size_t)bh*48 + t];
  int nm = nmark_g[bh];
  __syncthreads();
  if(t < nm){
    int u = mlist_g[(size_t)bh*48 + t];
    const double* s3 = scx_g + (size_t)bh*144 + 3*t;
    double mx = s3[0];
    if(s3[1] > mx) mx = s3[1];
    if(s3[2] > mx) mx = s3[2];
    Mv[u] = (float)mx - Ssum_g[(size_t)bh*48 + u]*(1.0f/4096.0f);
  }
  __syncthreads();
  float v = (t < 45) ? Mv[t] : -3e38f;
  int rank = 0;
  #pragma unroll
  for(int j=0;j<45;j++){
    float vj = __shfl(v, j, 64);
    rank += (vj > v) || (vj == v && j < (int)t);
  }
  if(t < 45) invrk[(size_t)bh*48 + t] = rank;
}

// =====================================================================
// Kernel 7: P2 — recompute q0 scores, attn = exp(s-m)/Z, PV via MFMA
// =====================================================================
__global__ __launch_bounds__(256) void pa_p2_attn(
    const uint16_t* __restrict__ q_f16, const uint16_t* __restrict__ khg,
    const uint16_t* __restrict__ v_t,
    const float* __restrict__ mzfin, const int* __restrict__ invrk,
    float* __restrict__ attn_out, float* __restrict__ ctx2){
  __shared__ alignas(16) short qf[48*64];
  __shared__ alignas(16) short kh[64*64];
  __shared__ alignas(16) short vT[64*64];
  __shared__ alignas(16) short Pl[48*64];
  int chunk = blockIdx.x, h = blockIdx.y, b = blockIdx.z;
  int tid = threadIdx.x, wid = tid >> 6, lane = tid & 63;
  const uint16_t* qsf = q_f16 + (((size_t)(b*16 + h))*96 + 48)*64;
  for(int oc=tid; oc<384; oc+=256){
    int sl = oc >> 3, o = oc & 7;
    lds_store8(qf, sl, 8, o, *(const short8*)(qsf + sl*64 + o*8));
  }
  float mreg[3][4], invz[3][4];
  int rrk[3][4];
  #pragma unroll
  for(int mf=0;mf<3;mf++)
    #pragma unroll
    for(int i=0;i<4;i++){
      int u = mf*16 + ((lane >> 4) << 2) + i;
      mreg[mf][i] = mzfin[(((size_t)(b*16 + h))*48 + u)*2 + 0];
      invz[mf][i] = 1.f / mzfin[(((size_t)(b*16 + h))*48 + u)*2 + 1];
      rrk[mf][i] = invrk[((size_t)(b*16 + h))*48 + u];
    }
  f32x4 ctx[3];
  #pragma unroll
  for(int mf=0;mf<3;mf++) ctx[mf] = (f32x4){0.f,0.f,0.f,0.f};
  int rsub = lane >> 3, soct = (lane & 7) ^ rsub;
  const uint16_t* khb = khg + (((size_t)(b*16 + h))*4096)*64;
  const uint16_t* vtb = v_t + (((size_t)(b*16 + h))*64)*4096;
  __syncthreads();
  for(int st=0; st<8; st++){
    int sg0 = chunk*512 + st*64;
    #pragma unroll
    for(int q=0;q<2;q++){
      int row = wid*16 + q*8;
      async16(khb + (size_t)(sg0 + row + rsub)*64 + soct*8, kh + row*64);
      async16(vtb + (size_t)(row + rsub)*4096 + sg0 + soct*8, vT + row*64);
    }
    __syncthreads();
    short8 Bf[2];
    #pragma unroll
    for(int k2=0;k2<2;k2++){
      int scol = wid*16 + (lane & 15);
      int oct = k2*4 + (lane >> 4);
      Bf[k2] = lds_frag(kh, scol, 8, oct);
    }
    #pragma unroll
    for(int mf=0;mf<3;mf++){
      short8 af[2];
      #pragma unroll
      for(int k2=0;k2<2;k2++){
        int row = mf*16 + (lane & 15);
        int oct = k2*4 + (lane >> 4);
        af[k2] = lds_frag(qf, row, 8, oct);
      }
      f32x4 a0 = (f32x4){0.f,0.f,0.f,0.f};
      #pragma unroll
      for(int k2=0;k2<2;k2++)
        a0 = mfma16h(af[k2], Bf[k2], a0);
      int scl = wid*16 + (lane & 15);
      #pragma unroll
      for(int i=0;i<4;i++){
        int u = mf*16 + ((lane >> 4) << 2) + i;
        float p = __expf(a0[i] - mreg[mf][i]) * invz[mf][i];
        if(u < 45){
          attn_out[(((size_t)(b*16 + h))*45 + rrk[mf][i])*4096 + sg0 + scl] = p;
        }
        int oct = scl >> 3;
        int o = (oct ^ (u & 7)) & 7;
        Pl[u*64 + o*8 + (scl & 7)] = (short)f2h(p);
      }
    }
    __syncthreads();
    #pragma unroll
    for(int k2=0;k2<2;k2++){
      int oct = k2*4 + (lane >> 4);
      int drow = wid*16 + (lane & 15);
      short8 bv = lds_frag(vT, drow, 8, oct);
      #pragma unroll
      for(int mf=0;mf<3;mf++){
        int row = mf*16 + (lane & 15);
        short8 ap = lds_frag(Pl, row, 8, oct);
        ctx[mf] = mfma16h(ap, bv, ctx[mf]);
      }
    }
    __syncthreads();
  }
  #pragma unroll
  for(int mf=0;mf<3;mf++)
    #pragma unroll
    for(int i=0;i<4;i++){
      int u = mf*16 + ((lane >> 4) << 2) + i;
      if(u < 45){
        int d = wid*16 + (lane & 15);
        ctx2[(((size_t)chunk*8 + b)*45 + rrk[mf][i])*1024 + h*64 + d] = ctx[mf][i];
      }
    }
}

// =====================================================================
// Kernel 8a: output partials — split-K by 4 for occupancy.
// =====================================================================
__global__ __launch_bounds__(256) void pa_out_part(
    const float* __restrict__ ctx2, const float* __restrict__ Wo,
    float* __restrict__ opart){
  __shared__ float cl[8][256];
  int bx = blockIdx.x, by = blockIdx.y, kc = blockIdx.z;
  int t = threadIdx.x;
  for(int e=t; e<8*256; e+=256){
    int rr = e >> 8, kk = e & 255;
    size_t grow = (size_t)by*8 + rr;
    float s = 0.f;
    #pragma unroll
    for(int c=0;c<8;c++) s += ctx2[((size_t)c*360 + grow)*1024 + kc*256 + kk];
    cl[rr][kk] = s;
  }
  __syncthreads();
  int quad = t & 63, rg = t >> 6;
  int n = bx*256 + quad*4;
  float acc[2][4];
  #pragma unroll
  for(int rr=0;rr<2;rr++)
    #pragma unroll
    for(int c=0;c<4;c++) acc[rr][c]=0.f;
  for(int k=0;k<256;k++){
    float4 w = *(const float4*)(Wo + (size_t)(kc*256 + k)*1024 + n);
    float c0 = cl[rg*2][k], c1 = cl[rg*2+1][k];
    acc[0][0] += c0*w.x; acc[0][1] += c0*w.y; acc[0][2] += c0*w.z; acc[0][3] += c0*w.w;
    acc[1][0] += c1*w.x; acc[1][1] += c1*w.y; acc[1][2] += c1*w.z; acc[1][3] += c1*w.w;
  }
  #pragma unroll
  for(int rr=0;rr<2;rr++){
    size_t grow = (size_t)by*8 + rg*2 + rr;
    #pragma unroll
    for(int c=0;c<4;c++)
      opart[((size_t)kc*360 + grow)*1024 + n + c] = acc[rr][c];
  }
}

// =====================================================================
// Kernel 8b: out = sum of 4 k-partials + bias (deterministic order)
// =====================================================================
__global__ __launch_bounds__(256) void pa_out_reduce(
    const float* __restrict__ opart, const float* __restrict__ bo,
    float* __restrict__ out){
  size_t e = (size_t)blockIdx.x*256 + threadIdx.x;
  const size_t N = (size_t)360*1024;
  if(e >= N) return;
  float s = ((opart[e] + opart[e + N]) + opart[e + 2*N]) + opart[e + 3*N];
  out[e] = s + bo[e & 1023];
}

// =====================================================================
extern "C" void kernel_launch(void* const* d_in, const int* in_sizes, int n_in,
                              void* d_out, int out_size, void* d_ws, size_t ws_size,
                              hipStream_t stream){
  const float* queries = (const float*)d_in[0];
  const float* keys    = (const float*)d_in[1];
  const float* values  = (const float*)d_in[2];
  const int*   perm    = (const int*)d_in[3];
  const float* Wq = (const float*)d_in[4]; const float* bq = (const float*)d_in[5];
  const float* Wk = (const float*)d_in[6]; const float* bk = (const float*)d_in[7];
  const float* Wv = (const float*)d_in[8]; const float* bv = (const float*)d_in[9];
  const float* Wo = (const float*)d_in[10]; const float* bo = (const float*)d_in[11];

  char* ws = (char*)d_ws;
  const size_t SZ = (size_t)33554432;          // 32M elements
  uint16_t* k_o   = (uint16_t*)(ws + SZ*4);                 // 67.1 MB
  uint16_t* v_t   = (uint16_t*)(ws + SZ*6);                 // 67.1 MB
  uint16_t* WkT   = (uint16_t*)(ws + SZ*8);                 // 2 MB
  uint16_t* WvT   = (uint16_t*)(ws + SZ*8 + 2097152);       // 2 MB
  float*    q_f32 = (float*)   (ws + SZ*8 + 4194304);       // 3.1 MB
  uint16_t* q_f16 = (uint16_t*)(ws + SZ*8 + 7340032);       // 1.6 MB

  // time-exclusive aliases (qpart dies before p1_stats writes stats;
  // opart written only after p2_attn):
  char* rg = ws + SZ*2;
  double* qpart   = (double*)rg;                      // 50,331,648 B
  float*  stats   = (float*)rg;                       // 12,582,912 B
  float*  mzfin   = (float*)(rg + 12582912);          //     49,152
  int*    invrk   = (int*)  (rg + 12632064);          //     24,576
  float*  ctx2    = (float*)(rg + 12656640);          // 11,796,480
  float*  Mv_g    = (float*)(rg + 24453120);          //     24,576
  float*  Ssum_g  = (float*)(rg + 24477696);          //     24,576
  int*    mlist_g = (int*)  (rg + 24502272);          //     24,576
  int*    clist_g = (int*)  (rg + 24526848);          //     73,728
  int*    nmark_g = (int*)  (rg + 24600576);          //        512
  double* scx_g   = (double*)(rg + 24601088);         //    147,456
  float*  opart   = (float*)(rg + 24748544);          //  5,898,240

  float* out  = (float*)d_out;
  float* attn = out + (size_t)360*1024;

  pa_prep_weights<<<dim3(1024,2), 256, 0, stream>>>(Wk, Wv, WkT, WvT);
  pa_q_stage1<<<dim3(8,8,8), 256, 0, stream>>>(queries, perm, Wq, qpart);
  pa_q_finalize<<<dim3(96,8), 256, 0, stream>>>(qpart, bq, q_f32, q_f16);
  pa_kv_gemm<<<dim3(2048,2), 256, 0, stream>>>(keys, values, WkT, WvT, bk, bv, k_o, v_t);
  pa_p1_stats<<<dim3(8,16,8), 256, 0, stream>>>(q_f16, k_o, stats);
  pa_sort_mark<<<dim3(16,8), 256, 0, stream>>>(stats, mzfin, Mv_g, Ssum_g, mlist_g, clist_g, nmark_g);
  pa_refine<<<dim3(135,16,8), 256, 0, stream>>>(keys, Wk, q_f32, mlist_g, clist_g, nmark_g, scx_g);
  pa_final_rank<<<dim3(16,8), 64, 0, stream>>>(Mv_g, Ssum_g, mlist_g, nmark_g, scx_g, invrk);
  pa_p2_attn<<<dim3(8,16,8), 256, 0, stream>>>(q_f16, k_o, v_t, mzfin, invrk, attn, ctx2);
  pa_out_part<<<dim3(4,45,4), 256, 0, stream>>>(ctx2, Wo, opart);
  pa_out_reduce<<<1440, 256, 0, stream>>>(opart, bo, out);
}